// Round 6
// baseline (26.952 us; speedup 1.0000x reference)
//
#include <hip/hip_runtime.h>
#include <hip/hip_bf16.h>
#include <math.h>

#define IMG 224
#define NLIB 1000
#define ZD 512
#define MAXK 8
#define NTHR 512
#define NBLK 196
#define MTAG 0x5EEDF00Du

// ---------------- ws layout (floats) ----------------
// [0, 1000)      dists                  (sc1-coherent)
// [1024, 1220)   a1 barrier slots (u32) (sc1-coherent)
// [1280, 1476)   a2 barrier slots (u32) (sc1-coherent)
// [1536, ...)    s0: 2 parts * MAXK * 3136
// next           s1: 4 parts * MAXK * 784
// next           s2: 8 parts * MAXK * 196

__device__ __forceinline__ int clampk(int k) {
    if (k < 1) k = 1;
    if (k > MAXK) k = MAXK;
    return k;
}

// device-coherent (cross-XCD) relaxed atomics — bypass non-coherent per-XCD L2
__device__ __forceinline__ void cgs_u32(unsigned* p, unsigned v) {
    __hip_atomic_store(p, v, __ATOMIC_RELAXED, __HIP_MEMORY_SCOPE_AGENT);
}
__device__ __forceinline__ unsigned cgl_u32(unsigned* p) {
    return __hip_atomic_load(p, __ATOMIC_RELAXED, __HIP_MEMORY_SCOPE_AGENT);
}
__device__ __forceinline__ void cgs_f32(float* p, float v) {
    __hip_atomic_store(p, v, __ATOMIC_RELAXED, __HIP_MEMORY_SCOPE_AGENT);
}
__device__ __forceinline__ float cgl_f32(const float* p) {
    return __hip_atomic_load((float*)p, __ATOMIC_RELAXED, __HIP_MEMORY_SCOPE_AGENT);
}

// arrive + wait: all NBLK blocks store MTAG to their slot, wave 0 latched-polls all.
// entry __syncthreads drains each wave's vmem (compiler emits s_waitcnt before s_barrier),
// so sc1 data stores are at the coherence point before the arrive store issues.
__device__ __forceinline__ void barrier_ar(unsigned* slots, int bid, int tid) {
    __syncthreads();
    if (tid == 0) cgs_u32(slots + bid, MTAG);
    if (tid < 64) {
        unsigned pend = 0;
#pragma unroll
        for (int q = 0; q < 4; ++q) { int i = q * 64 + tid; if (i < NBLK) pend |= 1u << q; }
        long guard = 0;
        for (;;) {
#pragma unroll
            for (int q = 0; q < 4; ++q) {
                int i = q * 64 + tid;
                if (pend & (1u << q))
                    if (cgl_u32(slots + i) == MTAG) pend &= ~(1u << q);
            }
            if (__all(pend == 0)) break;
            if (++guard > 100000000L) break;        // safety bail (never hit if correct)
            __builtin_amdgcn_s_sleep(4);
        }
    }
    __syncthreads();
    asm volatile("" ::: "memory");
}

// bilinear sample from an LDS window (already min-over-k + sqrt)
__device__ __forceinline__ float bilin(const float* __restrict__ msm, int Wl, int Win,
                                       int bx, int by, float scl, int gx, int gy) {
    float sxf = ((float)gx + 0.5f) * scl - 0.5f;
    float syf = ((float)gy + 0.5f) * scl - 0.5f;
    float fx = floorf(sxf), fy = floorf(syf);
    float wx = sxf - fx,    wy = syf - fy;
    int ix = (int)fx, iy = (int)fy;
    int x0c = min(max(ix, 0), Win - 1) - bx, x1c = min(max(ix + 1, 0), Win - 1) - bx;
    int y0c = min(max(iy, 0), Win - 1) - by, y1c = min(max(iy + 1, 0), Win - 1) - by;
    float v00 = msm[y0c * Wl + x0c], v10 = msm[y0c * Wl + x1c];
    float v01 = msm[y1c * Wl + x0c], v11 = msm[y1c * Wl + x1c];
    return (1.f - wy) * ((1.f - wx) * v00 + wx * v10) +
           wy * ((1.f - wx) * v01 + wx * v11);
}

__global__ void __launch_bounds__(NTHR) k_fused(
        const float* __restrict__ z,
        const float* __restrict__ f0, const float* __restrict__ f1,
        const float* __restrict__ f2,
        const float* __restrict__ zlib,
        const float* __restrict__ l0, const float* __restrict__ l1,
        const float* __restrict__ l2,
        const int* __restrict__ kp,
        float* __restrict__ out,
        float* __restrict__ dists, unsigned* __restrict__ a1, unsigned* __restrict__ a2,
        float* __restrict__ s0, float* __restrict__ s1, float* __restrict__ s2) {

    __shared__ float msm0[100], msm1[36], msm2[9];
    __shared__ float pre[32 * 32];
    __shared__ float mid[32 * 16];
    __shared__ float wk[17];

    int tid = threadIdx.x;
    int bid = blockIdx.x;
    int lane = tid & 63, wave = tid >> 6;
    int k = clampk(*kp);

    // block 0: restore a2 slots (stale MTAG from previous replay / 0xAA poison).
    // Safe: a2 is polled only after barrier-1, which requires a1[0]==MTAG, which is
    // stored after these stores are drained by barrier_ar's entry __syncthreads.
    if (bid == 0 && tid < NBLK) cgs_u32(a2 + tid, 0u);

    // blur weights (used in stage D)
    if (tid < 17) {
        float r = (float)(tid - 8) * 0.25f;     // t/sigma, sigma=4
        wk[tid] = expf(-0.5f * r * r);
    }

    // ---- Stage A: dists, one wave per entry (blocks 0..124 x 8 waves) ----
    int gw = bid * 8 + wave;
    if (bid < 125 && gw < NLIB) {
        const float4* row4 = (const float4*)(zlib + (size_t)gw * ZD);
        const float4* z4   = (const float4*)z;
        float4 a0 = row4[lane],      b0 = z4[lane];
        float4 a1v = row4[64 + lane], b1v = z4[64 + lane];
        float acc = 0.f, d;
        d = a0.x - b0.x; acc += d * d;  d = a0.y - b0.y; acc += d * d;
        d = a0.z - b0.z; acc += d * d;  d = a0.w - b0.w; acc += d * d;
        d = a1v.x - b1v.x; acc += d * d;  d = a1v.y - b1v.y; acc += d * d;
        d = a1v.z - b1v.z; acc += d * d;  d = a1v.w - b1v.w; acc += d * d;
#pragma unroll
        for (int off = 32; off > 0; off >>= 1) acc += __shfl_xor(acc, off, 64);
        if (lane == 0) cgs_f32(&dists[gw], sqrtf(acc));
    }

    // ================= barrier 1 =================
    barrier_ar(a1, bid, tid);

    // ---- Stage B+C: per-wave reg topk + exact float4 x 32ch partial sums ----
    int n0 = k * 1568, n1 = k * 784, n2 = k * 392;
    int njobs = n0 + n1 + n2;                   // = k*2744 <= 21952 < 196*512
    int j = bid * NTHR + tid;

    const float* fmp = nullptr; const float* lbp = nullptr; float* op = nullptr;
    int kk = 0, pq = 0, cbase = 0, HW = 0, Cfull = 0;
    bool valid = (j < njobs);
    if (valid) {
        if (j < n0) {
            int r = j;           kk = r / 1568; int q = r % 1568;
            int part = q / 784;  pq = q % 784;  cbase = part * 32;
            HW = 3136; Cfull = 64;  fmp = f0; lbp = l0;
            op = s0 + part * (MAXK * 3136) + kk * 3136;
        } else if (j < n0 + n1) {
            int r = j - n0;      kk = r / 784;  int q = r % 784;
            int part = q / 196;  pq = q % 196;  cbase = part * 32;
            HW = 784;  Cfull = 128; fmp = f1; lbp = l1;
            op = s1 + part * (MAXK * 784) + kk * 784;
        } else {
            int r = j - n0 - n1; kk = r / 392;  int q = r % 392;
            int part = q / 49;   pq = q % 49;   cbase = part * 32;
            HW = 196;  Cfull = 256; fmp = f2; lbp = l2;
            op = s2 + part * (MAXK * 196) + kk * 196;
        }
    }

    int waveBase = bid * NTHR + wave * 64;
    bool dotopk = (waveBase < njobs) || (bid == 0 && wave == 0);
    int myidx = 0;
    if (dotopk) {
        float vals[16];
#pragma unroll
        for (int q = 0; q < 16; ++q) {
            int e = lane + 64 * q;
            vals[q] = (e < NLIB) ? cgl_f32(&dists[e]) : 3.4e38f;
        }
        float ssum = 0.f;
        for (int it = 0; it < k; ++it) {
            float bv = 3.4e38f; int bi = 0x7fffffff;
#pragma unroll
            for (int q = 0; q < 16; ++q) {
                if (vals[q] < bv) { bv = vals[q]; bi = lane + 64 * q; }
            }
#pragma unroll
            for (int off = 1; off < 64; off <<= 1) {
                float ov = __shfl_xor(bv, off, 64);
                int   oi = __shfl_xor(bi, off, 64);
                if (ov < bv || (ov == bv && oi < bi)) { bv = ov; bi = oi; }
            }
#pragma unroll
            for (int q = 0; q < 16; ++q) {
                if (lane + 64 * q == bi) vals[q] = 3.4e38f;
            }
            if (it == kk) myidx = bi;
            ssum += bv;
        }
        if (bid == 0 && tid == 0) out[0] = ssum / (float)k;
    }

    if (valid) {
        const float4* lb4 = (const float4*)(lbp + (size_t)myidx * (size_t)Cfull * HW
                                                + (size_t)cbase * HW);
        const float4* fb4 = (const float4*)(fmp + (size_t)cbase * HW);
        int HW4 = HW >> 2;
        float ax = 0.f, ay = 0.f, az = 0.f, aw = 0.f;
#pragma unroll
        for (int c = 0; c < 32; ++c) {
            float4 a = lb4[c * HW4 + pq];
            float4 b = fb4[c * HW4 + pq];
            float dx = a.x - b.x, dy = a.y - b.y, dz = a.z - b.z, dw = a.w - b.w;
            ax += dx * dx; ay += dy * dy; az += dz * dz; aw += dw * dw;
        }
        float* o = op + 4 * pq;
        cgs_f32(o + 0, ax); cgs_f32(o + 1, ay);
        cgs_f32(o + 2, az); cgs_f32(o + 3, aw);
    }

    // ================= barrier 2 =================
    barrier_ar(a2, bid, tid);

    // restore own a1 slot for the next launch (safe: passing b2 implies every
    // block's b1 poll already completed)
    if (tid == 0) cgs_u32(a1 + bid, 0u);

    // ---- Stage D: per-tile min+sqrt window staging, upsample, blur (LDS) ----
    int tx = bid % 14, ty = bid / 14;
    int x0 = tx * 16, y0 = ty * 16;
    int b0x = x0 / 4 - 3,  b0y = y0 / 4 - 3;
    int b1x = x0 / 8 - 2,  b1y = y0 / 8 - 2;
    int b2x = x0 / 16 - 1, b2y = y0 / 16 - 1;

    if (tid >= 64 && tid < 64 + 145) {
        int i = tid - 64;
        float m = 3.4e38f;
        if (i < 100) {
            int ly = i / 10, lx = i % 10;
            int gx = min(max(b0x + lx, 0), 55), gy = min(max(b0y + ly, 0), 55);
            int p = gy * 56 + gx;
            for (int kq = 0; kq < k; ++kq) {
                float v = cgl_f32(&s0[kq * 3136 + p])
                        + cgl_f32(&s0[MAXK * 3136 + kq * 3136 + p]);
                m = fminf(m, v);
            }
            msm0[i] = sqrtf(m);
        } else if (i < 136) {
            int r = i - 100; int ly = r / 6, lx = r % 6;
            int gx = min(max(b1x + lx, 0), 27), gy = min(max(b1y + ly, 0), 27);
            int p = gy * 28 + gx;
            for (int kq = 0; kq < k; ++kq) {
                float v = 0.f;
#pragma unroll
                for (int part = 0; part < 4; ++part)
                    v += cgl_f32(&s1[part * (MAXK * 784) + kq * 784 + p]);
                m = fminf(m, v);
            }
            msm1[r] = sqrtf(m);
        } else {
            int r = i - 136; int ly = r / 3, lx = r % 3;
            int gx = min(max(b2x + lx, 0), 13), gy = min(max(b2y + ly, 0), 13);
            int p = gy * 14 + gx;
            for (int kq = 0; kq < k; ++kq) {
                float v = 0.f;
#pragma unroll
                for (int part = 0; part < 8; ++part)
                    v += cgl_f32(&s2[part * (MAXK * 196) + kq * 196 + p]);
                m = fminf(m, v);
            }
            msm2[r] = sqrtf(m);
        }
    }
    __syncthreads();

    float wsum = 0.f;
#pragma unroll
    for (int t = 0; t < 17; ++t) wsum += wk[t];
    float inv2 = 1.f / (wsum * wsum);

    for (int i = tid; i < 32 * 32; i += NTHR) {
        int lx = i % 32, ly = i / 32;
        int gx = x0 - 8 + lx, gy = y0 - 8 + ly;
        float v = 0.f;
        if ((unsigned)gx < (unsigned)IMG && (unsigned)gy < (unsigned)IMG) {
            v = bilin(msm0, 10, 56, b0x, b0y, 0.25f,   gx, gy)
              + bilin(msm1, 6,  28, b1x, b1y, 0.125f,  gx, gy)
              + bilin(msm2, 3,  14, b2x, b2y, 0.0625f, gx, gy);
        }
        pre[i] = v;
    }
    __syncthreads();

    if (tid < 32 * 16) {
        int cx = tid % 16, ly = tid / 16;
        float acc = 0.f;
#pragma unroll
        for (int t = 0; t < 17; ++t) acc += wk[t] * pre[ly * 32 + cx + t];
        mid[ly * 16 + cx] = acc;
    }
    __syncthreads();

    if (tid < 16 * 16) {
        int ox = tid % 16, oy = tid / 16;
        float acc = 0.f;
#pragma unroll
        for (int t = 0; t < 17; ++t) acc += wk[t] * mid[(oy + t) * 16 + ox];
        out[1 + (y0 + oy) * IMG + (x0 + ox)] = acc * inv2;
    }
}

extern "C" void kernel_launch(void* const* d_in, const int* in_sizes, int n_in,
                              void* d_out, int out_size, void* d_ws, size_t ws_size,
                              hipStream_t stream) {
    const float* z    = (const float*)d_in[0];
    const float* f0   = (const float*)d_in[1];
    const float* f1   = (const float*)d_in[2];
    const float* f2   = (const float*)d_in[3];
    const float* zlib = (const float*)d_in[4];
    const float* l0   = (const float*)d_in[5];
    const float* l1   = (const float*)d_in[6];
    const float* l2   = (const float*)d_in[7];
    const int*   kp   = (const int*)d_in[8];
    float* out = (float*)d_out;

    float*    ws    = (float*)d_ws;
    float*    dists = ws;                       // 1000
    unsigned* a1    = (unsigned*)(ws + 1024);   // 196
    unsigned* a2    = (unsigned*)(ws + 1280);   // 196
    float*    s0    = ws + 1536;                // 2*MAXK*3136
    float*    s1    = s0 + 2 * MAXK * 3136;     // 4*MAXK*784
    float*    s2    = s1 + 4 * MAXK * 784;      // 8*MAXK*196

    k_fused<<<NBLK, NTHR, 0, stream>>>(z, f0, f1, f2, zlib, l0, l1, l2, kp,
                                       out, dists, a1, a2, s0, s1, s2);
}

// Round 7
// 24.406 us; speedup vs baseline: 1.1043x; 1.1043x over previous
//
#include <hip/hip_runtime.h>
#include <hip/hip_bf16.h>
#include <math.h>

#define IMG 224
#define NLIB 1000
#define ZD 512
#define MAXK 8
#define NTHR 512
#define STHR 256
#define SBLK 172    // ceil(MAXK*2744 / 64 wave-jobs / 4 waves) -> 172 blocks covers k=8

// ---------------- ws layout (floats) ----------------
// [0, 1000)            dists
// [1024, ...)          s0: 2 parts * MAXK * 3136   (scale 56, C=64 -> 2x32ch)
// next 4*MAXK*784      s1: 4 parts * MAXK * 784    (scale 28, C=128 -> 4x32ch)
// next 8*MAXK*196      s2: 8 parts * MAXK * 196    (scale 14, C=256 -> 8x32ch)

__device__ __forceinline__ int clampk(int k) {
    if (k < 1) k = 1;
    if (k > MAXK) k = MAXK;
    return k;
}

// ---- K1: dists[e] = ||zlib[e] - z||, one wave per entry ----
__global__ void __launch_bounds__(NTHR) k_dist(const float* __restrict__ z,
                                               const float* __restrict__ zlib,
                                               float* __restrict__ dists) {
    int lane = threadIdx.x & 63, wave = threadIdx.x >> 6;
    int gw = blockIdx.x * (NTHR / 64) + wave;
    if (gw >= NLIB) return;
    const float4* row4 = (const float4*)(zlib + (size_t)gw * ZD);
    const float4* z4   = (const float4*)z;
    float4 a0 = row4[lane],      b0 = z4[lane];
    float4 a1 = row4[64 + lane], b1 = z4[64 + lane];
    float acc = 0.f, d;
    d = a0.x - b0.x; acc += d * d;  d = a0.y - b0.y; acc += d * d;
    d = a0.z - b0.z; acc += d * d;  d = a0.w - b0.w; acc += d * d;
    d = a1.x - b1.x; acc += d * d;  d = a1.y - b1.y; acc += d * d;
    d = a1.z - b1.z; acc += d * d;  d = a1.w - b1.w; acc += d * d;
#pragma unroll
    for (int off = 32; off > 0; off >>= 1) acc += __shfl_xor(acc, off, 64);
    if (lane == 0) dists[gw] = sqrtf(acc);
}

// ---- K2: per-wave reg topk + block-major-spread float4 x 32ch partial sums ----
__global__ void __launch_bounds__(STHR) k_score(
        const float* __restrict__ f0, const float* __restrict__ f1,
        const float* __restrict__ f2,
        const float* __restrict__ l0, const float* __restrict__ l1,
        const float* __restrict__ l2,
        const float* __restrict__ dists, const int* __restrict__ kp,
        float* __restrict__ out,
        float* __restrict__ s0, float* __restrict__ s1, float* __restrict__ s2) {

    int tid = threadIdx.x;
    int lane = tid & 63, wv = tid >> 6;
    int k = clampk(*kp);

    int n0 = k * 1568, n1 = k * 784, n2 = k * 392;
    int njobs = n0 + n1 + n2;               // k*2744
    int nwj = (njobs + 63) >> 6;            // 64-job wave-units
    int s = blockIdx.x + SBLK * wv;         // block-major slot -> spreads across CUs
    bool wvalid = (s < nwj);
    bool scorer = (blockIdx.x == 0 && wv == 0);
    if (!wvalid && !scorer) return;

    // ---- wave-parallel top-k fully in registers (all 8 indices kept) ----
    float vals[16];
#pragma unroll
    for (int q = 0; q < 16; ++q) {
        int e = lane + 64 * q;
        vals[q] = (e < NLIB) ? dists[e] : 3.4e38f;
    }
    int idxr[8];
    float ssum = 0.f;
#pragma unroll
    for (int it = 0; it < 8; ++it) {
        if (it < k) {
            float bv = 3.4e38f; int bi = 0x7fffffff;
#pragma unroll
            for (int q = 0; q < 16; ++q) {
                if (vals[q] < bv) { bv = vals[q]; bi = lane + 64 * q; }
            }
#pragma unroll
            for (int off = 1; off < 64; off <<= 1) {
                float ov = __shfl_xor(bv, off, 64);
                int   oi = __shfl_xor(bi, off, 64);
                if (ov < bv || (ov == bv && oi < bi)) { bv = ov; bi = oi; }
            }
#pragma unroll
            for (int q = 0; q < 16; ++q) {
                if (lane + 64 * q == bi) vals[q] = 3.4e38f;
            }
            idxr[it] = bi; ssum += bv;
        } else {
            idxr[it] = 0;
        }
    }
    if (scorer && lane == 0) out[0] = ssum / (float)k;
    if (!wvalid) return;

    int j = s * 64 + lane;                  // consecutive jobs across lanes -> coalesced
    if (j >= njobs) return;

    // decode job
    const float* fmp; const float* lbp; float* op;
    int kk, pq, cbase, HW, Cfull;
    if (j < n0) {
        int r = j;           kk = r / 1568; int q = r % 1568;
        int part = q / 784;  pq = q % 784;  cbase = part * 32;
        HW = 3136; Cfull = 64;  fmp = f0; lbp = l0;
        op = s0 + part * (MAXK * 3136) + kk * 3136;
    } else if (j < n0 + n1) {
        int r = j - n0;      kk = r / 784;  int q = r % 784;
        int part = q / 196;  pq = q % 196;  cbase = part * 32;
        HW = 784;  Cfull = 128; fmp = f1; lbp = l1;
        op = s1 + part * (MAXK * 784) + kk * 784;
    } else {
        int r = j - n0 - n1; kk = r / 392;  int q = r % 392;
        int part = q / 49;   pq = q % 49;   cbase = part * 32;
        HW = 196;  Cfull = 256; fmp = f2; lbp = l2;
        op = s2 + part * (MAXK * 196) + kk * 196;
    }
    int myidx = 0;
#pragma unroll
    for (int it = 0; it < 8; ++it) if (it == kk) myidx = idxr[it];

    const float4* lb4 = (const float4*)(lbp + (size_t)myidx * (size_t)Cfull * HW
                                            + (size_t)cbase * HW);
    const float4* fb4 = (const float4*)(fmp + (size_t)cbase * HW);
    int HW4 = HW >> 2;
    float ax = 0.f, ay = 0.f, az = 0.f, aw = 0.f;
#pragma unroll
    for (int c = 0; c < 32; ++c) {
        float4 a = lb4[c * HW4 + pq];
        float4 b = fb4[c * HW4 + pq];
        float dx = a.x - b.x, dy = a.y - b.y, dz = a.z - b.z, dw = a.w - b.w;
        ax += dx * dx; ay += dy * dy; az += dz * dz; aw += dw * dw;
    }
    float4 r; r.x = ax; r.y = ay; r.z = az; r.w = aw;
    ((float4*)op)[pq] = r;
}

// bilinear sample from an LDS window (already min-over-k + sqrt)
__device__ __forceinline__ float bilin(const float* __restrict__ msm, int Wl, int Win,
                                       int bx, int by, float scl, int gx, int gy) {
    float sxf = ((float)gx + 0.5f) * scl - 0.5f;
    float syf = ((float)gy + 0.5f) * scl - 0.5f;
    float fx = floorf(sxf), fy = floorf(syf);
    float wx = sxf - fx,    wy = syf - fy;
    int ix = (int)fx, iy = (int)fy;
    int x0c = min(max(ix, 0), Win - 1) - bx, x1c = min(max(ix + 1, 0), Win - 1) - bx;
    int y0c = min(max(iy, 0), Win - 1) - by, y1c = min(max(iy + 1, 0), Win - 1) - by;
    float v00 = msm[y0c * Wl + x0c], v10 = msm[y0c * Wl + x1c];
    float v01 = msm[y1c * Wl + x0c], v11 = msm[y1c * Wl + x1c];
    return (1.f - wy) * ((1.f - wx) * v00 + wx * v10) +
           wy * ((1.f - wx) * v01 + wx * v11);
}

// ---- K3: per-tile min+sqrt window staging, upsample, blur (all LDS) ----
__global__ void __launch_bounds__(NTHR) k_tile(
        const float* __restrict__ s0, const float* __restrict__ s1,
        const float* __restrict__ s2, const int* __restrict__ kp,
        float* __restrict__ out) {

    __shared__ float msm0[100];     // 10x10 window, scale 56
    __shared__ float msm1[36];      // 6x6 window, scale 28
    __shared__ float msm2[9];       // 3x3 window, scale 14
    __shared__ float pre[32 * 32];
    __shared__ float mid[32 * 16];
    __shared__ float wk[17];

    int tid = threadIdx.x;
    int k = clampk(*kp);
    int tx = blockIdx.x % 14, ty = blockIdx.x / 14;
    int x0 = tx * 16, y0 = ty * 16;
    int b0x = x0 / 4 - 3,  b0y = y0 / 4 - 3;
    int b1x = x0 / 8 - 2,  b1y = y0 / 8 - 2;
    int b2x = x0 / 16 - 1, b2y = y0 / 16 - 1;

    if (tid < 17) {
        float r = (float)(tid - 8) * 0.25f;     // t/sigma, sigma=4
        wk[tid] = expf(-0.5f * r * r);
    }

    // stage windows: min over k of (sum of 32ch parts), then sqrt
    if (tid >= 64 && tid < 64 + 145) {
        int i = tid - 64;
        float m = 3.4e38f;
        if (i < 100) {
            int ly = i / 10, lx = i % 10;
            int gx = min(max(b0x + lx, 0), 55), gy = min(max(b0y + ly, 0), 55);
            int p = gy * 56 + gx;
            for (int kk = 0; kk < k; ++kk) {
                float v = s0[kk * 3136 + p] + s0[MAXK * 3136 + kk * 3136 + p];
                m = fminf(m, v);
            }
            msm0[i] = sqrtf(m);
        } else if (i < 136) {
            int r = i - 100; int ly = r / 6, lx = r % 6;
            int gx = min(max(b1x + lx, 0), 27), gy = min(max(b1y + ly, 0), 27);
            int p = gy * 28 + gx;
            for (int kk = 0; kk < k; ++kk) {
                float v = 0.f;
#pragma unroll
                for (int part = 0; part < 4; ++part)
                    v += s1[part * (MAXK * 784) + kk * 784 + p];
                m = fminf(m, v);
            }
            msm1[r] = sqrtf(m);
        } else {
            int r = i - 136; int ly = r / 3, lx = r % 3;
            int gx = min(max(b2x + lx, 0), 13), gy = min(max(b2y + ly, 0), 13);
            int p = gy * 14 + gx;
            for (int kk = 0; kk < k; ++kk) {
                float v = 0.f;
#pragma unroll
                for (int part = 0; part < 8; ++part)
                    v += s2[part * (MAXK * 196) + kk * 196 + p];
                m = fminf(m, v);
            }
            msm2[r] = sqrtf(m);
        }
    }
    __syncthreads();

    float wsum = 0.f;
#pragma unroll
    for (int t = 0; t < 17; ++t) wsum += wk[t];
    float inv2 = 1.f / (wsum * wsum);

    // upsample + sum of 3 scales into 32x32 halo tile (zero outside image)
    for (int i = tid; i < 32 * 32; i += NTHR) {
        int lx = i % 32, ly = i / 32;
        int gx = x0 - 8 + lx, gy = y0 - 8 + ly;
        float v = 0.f;
        if ((unsigned)gx < (unsigned)IMG && (unsigned)gy < (unsigned)IMG) {
            v = bilin(msm0, 10, 56, b0x, b0y, 0.25f,   gx, gy)
              + bilin(msm1, 6,  28, b1x, b1y, 0.125f,  gx, gy)
              + bilin(msm2, 3,  14, b2x, b2y, 0.0625f, gx, gy);
        }
        pre[i] = v;
    }
    __syncthreads();

    // horizontal blur: 32 rows x 16 center cols
    if (tid < 32 * 16) {
        int cx = tid % 16, ly = tid / 16;
        float acc = 0.f;
#pragma unroll
        for (int t = 0; t < 17; ++t) acc += wk[t] * pre[ly * 32 + cx + t];
        mid[ly * 16 + cx] = acc;
    }
    __syncthreads();

    // vertical blur + store
    if (tid < 16 * 16) {
        int ox = tid % 16, oy = tid / 16;
        float acc = 0.f;
#pragma unroll
        for (int t = 0; t < 17; ++t) acc += wk[t] * mid[(oy + t) * 16 + ox];
        out[1 + (y0 + oy) * IMG + (x0 + ox)] = acc * inv2;
    }
}

extern "C" void kernel_launch(void* const* d_in, const int* in_sizes, int n_in,
                              void* d_out, int out_size, void* d_ws, size_t ws_size,
                              hipStream_t stream) {
    const float* z    = (const float*)d_in[0];
    const float* f0   = (const float*)d_in[1];
    const float* f1   = (const float*)d_in[2];
    const float* f2   = (const float*)d_in[3];
    const float* zlib = (const float*)d_in[4];
    const float* l0   = (const float*)d_in[5];
    const float* l1   = (const float*)d_in[6];
    const float* l2   = (const float*)d_in[7];
    const int*   kp   = (const int*)d_in[8];
    float* out = (float*)d_out;

    float* ws    = (float*)d_ws;
    float* dists = ws;                          // 1000
    float* s0    = ws + 1024;                   // 2*MAXK*3136
    float* s1    = s0 + 2 * MAXK * 3136;        // 4*MAXK*784
    float* s2    = s1 + 4 * MAXK * 784;         // 8*MAXK*196

    k_dist<<<(NLIB + 7) / 8, NTHR, 0, stream>>>(z, zlib, dists);
    k_score<<<SBLK, STHR, 0, stream>>>(f0, f1, f2, l0, l1, l2, dists, kp, out,
                                       s0, s1, s2);
    k_tile<<<196, NTHR, 0, stream>>>(s0, s1, s2, kp, out);
}

// Round 8
// 23.873 us; speedup vs baseline: 1.1290x; 1.0223x over previous
//
#include <hip/hip_runtime.h>
#include <hip/hip_bf16.h>
#include <math.h>

#define IMG 224
#define NLIB 1000
#define ZD 512
#define MAXK 8
#define NTHR 512
#define KA_BLK 125
#define KB_BLK 196
#define MTAG 0x5EEDF00Du

// ---------------- ws layout (floats) ----------------
// [0, 1000)      dists (sc1)
// [1000, 1125)   d1 arrival slots u32 (KA)
// [1152, 1160)   idxs (int[8], plain)
// [1184, 1380)   b1 arrival slots u32 (KB)
// [1408, 1604)   rel release slots u32 (KB)
// [1664, ...)    s0: 2 parts * MAXK * 3136
// next           s1: 4 parts * MAXK * 784
// next           s2: 8 parts * MAXK * 196

__device__ __forceinline__ int clampk(int k) {
    if (k < 1) k = 1;
    if (k > MAXK) k = MAXK;
    return k;
}

// device-coherent relaxed atomics (bypass non-coherent per-XCD L2) — R6-validated
__device__ __forceinline__ void cgs_u32(unsigned* p, unsigned v) {
    __hip_atomic_store(p, v, __ATOMIC_RELAXED, __HIP_MEMORY_SCOPE_AGENT);
}
__device__ __forceinline__ unsigned cgl_u32(unsigned* p) {
    return __hip_atomic_load(p, __ATOMIC_RELAXED, __HIP_MEMORY_SCOPE_AGENT);
}
__device__ __forceinline__ void cgs_f32(float* p, float v) {
    __hip_atomic_store(p, v, __ATOMIC_RELAXED, __HIP_MEMORY_SCOPE_AGENT);
}
__device__ __forceinline__ float cgl_f32(const float* p) {
    return __hip_atomic_load((float*)p, __ATOMIC_RELAXED, __HIP_MEMORY_SCOPE_AGENT);
}

// ---- KA: dists + single-poller top-k ----
__global__ void __launch_bounds__(NTHR) k_dist_topk(
        const float* __restrict__ z, const float* __restrict__ zlib,
        const int* __restrict__ kp,
        float* __restrict__ dists, unsigned* __restrict__ d1,
        int* __restrict__ idxs, float* __restrict__ out) {
    int tid = threadIdx.x, lane = tid & 63, wave = tid >> 6, bid = blockIdx.x;
    int k = clampk(*kp);

    int gw = bid * 8 + wave;                    // 125*8 = 1000 exactly
    {
        const float4* row4 = (const float4*)(zlib + (size_t)gw * ZD);
        const float4* z4   = (const float4*)z;
        float4 a0 = row4[lane],      b0 = z4[lane];
        float4 a1 = row4[64 + lane], b1 = z4[64 + lane];
        float acc = 0.f, d;
        d = a0.x - b0.x; acc += d * d;  d = a0.y - b0.y; acc += d * d;
        d = a0.z - b0.z; acc += d * d;  d = a0.w - b0.w; acc += d * d;
        d = a1.x - b1.x; acc += d * d;  d = a1.y - b1.y; acc += d * d;
        d = a1.z - b1.z; acc += d * d;  d = a1.w - b1.w; acc += d * d;
#pragma unroll
        for (int off = 32; off > 0; off >>= 1) acc += __shfl_xor(acc, off, 64);
        if (lane == 0) cgs_f32(&dists[gw], sqrtf(acc));
    }
    __syncthreads();                            // drains this block's sc1 stores
    if (tid == 0) cgs_u32(d1 + bid, MTAG);
    if (bid != 0 || wave != 0) return;

    // block 0 wave 0: poll all 125 arrival slots (2 per lane)
    {
        unsigned pend = 0;
#pragma unroll
        for (int q = 0; q < 2; ++q) { int i = q * 64 + lane; if (i < KA_BLK) pend |= 1u << q; }
        long guard = 0;
        for (;;) {
#pragma unroll
            for (int q = 0; q < 2; ++q) {
                int i = q * 64 + lane;
                if ((pend & (1u << q)) && cgl_u32(d1 + i) == MTAG) pend &= ~(1u << q);
            }
            if (__all(pend == 0)) break;
            if (++guard > 100000000L) break;
            __builtin_amdgcn_s_sleep(2);
        }
    }
    asm volatile("" ::: "memory");

    // top-k in registers (single wave)
    float vals[16];
#pragma unroll
    for (int q = 0; q < 16; ++q) {
        int e = lane + 64 * q;
        vals[q] = (e < NLIB) ? cgl_f32(&dists[e]) : 3.4e38f;
    }
    float ssum = 0.f;
    for (int it = 0; it < k; ++it) {
        float bv = 3.4e38f; int bi = 0x7fffffff;
#pragma unroll
        for (int q = 0; q < 16; ++q) {
            if (vals[q] < bv) { bv = vals[q]; bi = lane + 64 * q; }
        }
#pragma unroll
        for (int off = 1; off < 64; off <<= 1) {
            float ov = __shfl_xor(bv, off, 64);
            int   oi = __shfl_xor(bi, off, 64);
            if (ov < bv || (ov == bv && oi < bi)) { bv = ov; bi = oi; }
        }
#pragma unroll
        for (int q = 0; q < 16; ++q) {
            if (lane + 64 * q == bi) vals[q] = 3.4e38f;
        }
        if (lane == 0) idxs[it] = bi;           // plain store, next dispatch reads
        ssum += bv;
    }
    if (lane == 0) out[0] = ssum / (float)k;

    // reset arrival slots for next replay (only this wave ever reads them)
#pragma unroll
    for (int q = 0; q < 2; ++q) { int i = q * 64 + lane; if (i < KA_BLK) cgs_u32(d1 + i, 0u); }
}

// bilinear sample from an LDS window (already min-over-k + sqrt)
__device__ __forceinline__ float bilin(const float* __restrict__ msm, int Wl, int Win,
                                       int bx, int by, float scl, int gx, int gy) {
    float sxf = ((float)gx + 0.5f) * scl - 0.5f;
    float syf = ((float)gy + 0.5f) * scl - 0.5f;
    float fx = floorf(sxf), fy = floorf(syf);
    float wx = sxf - fx,    wy = syf - fy;
    int ix = (int)fx, iy = (int)fy;
    int x0c = min(max(ix, 0), Win - 1) - bx, x1c = min(max(ix + 1, 0), Win - 1) - bx;
    int y0c = min(max(iy, 0), Win - 1) - by, y1c = min(max(iy + 1, 0), Win - 1) - by;
    float v00 = msm[y0c * Wl + x0c], v10 = msm[y0c * Wl + x1c];
    float v01 = msm[y1c * Wl + x0c], v11 = msm[y1c * Wl + x1c];
    return (1.f - wy) * ((1.f - wx) * v00 + wx * v10) +
           wy * ((1.f - wx) * v01 + wx * v11);
}

// ---- KB: Stage C gather + light barrier + Stage D tile ----
__global__ void __launch_bounds__(NTHR) k_main(
        const float* __restrict__ f0, const float* __restrict__ f1,
        const float* __restrict__ f2,
        const float* __restrict__ l0, const float* __restrict__ l1,
        const float* __restrict__ l2,
        const int* __restrict__ idxs, const int* __restrict__ kp,
        float* __restrict__ out,
        unsigned* __restrict__ b1, unsigned* __restrict__ rel,
        float* __restrict__ s0, float* __restrict__ s1, float* __restrict__ s2) {

    __shared__ float msm0[100], msm1[36], msm2[9];
    __shared__ float pre[32 * 32];
    __shared__ float mid[32 * 16];
    __shared__ float wk[17];

    int tid = threadIdx.x, lane = tid & 63, wv = tid >> 6, bid = blockIdx.x;
    int k = clampk(*kp);

    if (tid < 17) {
        float r = (float)(tid - 8) * 0.25f;     // t/sigma, sigma=4
        wk[tid] = expf(-0.5f * r * r);
    }

    // ---- Stage C: exact partial channel-L2 sums, block-major spread ----
    int n0 = k * 1568, n1 = k * 784, n2 = k * 392;
    int njobs = n0 + n1 + n2;                   // k*2744
    int nwj = (njobs + 63) >> 6;
    int s = bid + KB_BLK * wv;
    if (s < nwj) {
        int j = s * 64 + lane;
        if (j < njobs) {
            const float* fmp; const float* lbp; float* op;
            int kk, pq, cbase, HW, Cfull;
            if (j < n0) {
                int r = j;           kk = r / 1568; int q = r % 1568;
                int part = q / 784;  pq = q % 784;  cbase = part * 32;
                HW = 3136; Cfull = 64;  fmp = f0; lbp = l0;
                op = s0 + part * (MAXK * 3136) + kk * 3136;
            } else if (j < n0 + n1) {
                int r = j - n0;      kk = r / 784;  int q = r % 784;
                int part = q / 196;  pq = q % 196;  cbase = part * 32;
                HW = 784;  Cfull = 128; fmp = f1; lbp = l1;
                op = s1 + part * (MAXK * 784) + kk * 784;
            } else {
                int r = j - n0 - n1; kk = r / 392;  int q = r % 392;
                int part = q / 49;   pq = q % 49;   cbase = part * 32;
                HW = 196;  Cfull = 256; fmp = f2; lbp = l2;
                op = s2 + part * (MAXK * 196) + kk * 196;
            }
            int myidx = idxs[kk];
            const float4* lb4 = (const float4*)(lbp + (size_t)myidx * (size_t)Cfull * HW
                                                    + (size_t)cbase * HW);
            const float4* fb4 = (const float4*)(fmp + (size_t)cbase * HW);
            int HW4 = HW >> 2;
            float ax = 0.f, ay = 0.f, az = 0.f, aw = 0.f;
#pragma unroll
            for (int c = 0; c < 32; ++c) {
                float4 a = lb4[c * HW4 + pq];
                float4 b = fb4[c * HW4 + pq];
                float dx = a.x - b.x, dy = a.y - b.y, dz = a.z - b.z, dw = a.w - b.w;
                ax += dx * dx; ay += dy * dy; az += dz * dz; aw += dw * dw;
            }
            float* o = op + 4 * pq;
            cgs_f32(o + 0, ax); cgs_f32(o + 1, ay);
            cgs_f32(o + 2, az); cgs_f32(o + 3, aw);
        }
    }

    // ---- light barrier: 1 arrival/block; block0.wave0 masters; per-block release ----
    __syncthreads();                            // drains this block's sc1 stores
    if (tid == 0) cgs_u32(b1 + bid, MTAG);
    if (bid == 0 && tid < 64) {
        unsigned pend = 0;
#pragma unroll
        for (int q = 0; q < 4; ++q) { int i = q * 64 + tid; if (i < KB_BLK) pend |= 1u << q; }
        long guard = 0;
        for (;;) {
#pragma unroll
            for (int q = 0; q < 4; ++q) {
                int i = q * 64 + tid;
                if ((pend & (1u << q)) && cgl_u32(b1 + i) == MTAG) pend &= ~(1u << q);
            }
            if (__all(pend == 0)) break;
            if (++guard > 100000000L) break;
            __builtin_amdgcn_s_sleep(2);
        }
#pragma unroll
        for (int q = 0; q < 4; ++q) { int i = q * 64 + tid; if (i < KB_BLK) cgs_u32(rel + i, MTAG); }
    }
    if (tid == 0) {
        long guard = 0;
        while (cgl_u32(rel + bid) != MTAG) {
            if (++guard > 100000000L) break;
            __builtin_amdgcn_s_sleep(2);
        }
    }
    __syncthreads();
    asm volatile("" ::: "memory");
    if (tid == 0) { cgs_u32(rel + bid, 0u); cgs_u32(b1 + bid, 0u); }   // self-reset

    // ---- Stage D: per-tile min+sqrt window staging, upsample, blur ----
    int tx = bid % 14, ty = bid / 14;
    int x0 = tx * 16, y0 = ty * 16;
    int b0x = x0 / 4 - 3,  b0y = y0 / 4 - 3;
    int b1x = x0 / 8 - 2,  b1y = y0 / 8 - 2;
    int b2x = x0 / 16 - 1, b2y = y0 / 16 - 1;

    if (tid >= 64 && tid < 64 + 145) {
        int i = tid - 64;
        float m = 3.4e38f;
        if (i < 100) {
            int ly = i / 10, lx = i % 10;
            int gx = min(max(b0x + lx, 0), 55), gy = min(max(b0y + ly, 0), 55);
            int p = gy * 56 + gx;
            for (int kq = 0; kq < k; ++kq) {
                float v = cgl_f32(&s0[kq * 3136 + p])
                        + cgl_f32(&s0[MAXK * 3136 + kq * 3136 + p]);
                m = fminf(m, v);
            }
            msm0[i] = sqrtf(m);
        } else if (i < 136) {
            int r = i - 100; int ly = r / 6, lx = r % 6;
            int gx = min(max(b1x + lx, 0), 27), gy = min(max(b1y + ly, 0), 27);
            int p = gy * 28 + gx;
            for (int kq = 0; kq < k; ++kq) {
                float v = 0.f;
#pragma unroll
                for (int part = 0; part < 4; ++part)
                    v += cgl_f32(&s1[part * (MAXK * 784) + kq * 784 + p]);
                m = fminf(m, v);
            }
            msm1[r] = sqrtf(m);
        } else {
            int r = i - 136; int ly = r / 3, lx = r % 3;
            int gx = min(max(b2x + lx, 0), 13), gy = min(max(b2y + ly, 0), 13);
            int p = gy * 14 + gx;
            for (int kq = 0; kq < k; ++kq) {
                float v = 0.f;
#pragma unroll
                for (int part = 0; part < 8; ++part)
                    v += cgl_f32(&s2[part * (MAXK * 196) + kq * 196 + p]);
                m = fminf(m, v);
            }
            msm2[r] = sqrtf(m);
        }
    }
    __syncthreads();

    float wsum = 0.f;
#pragma unroll
    for (int t = 0; t < 17; ++t) wsum += wk[t];
    float inv2 = 1.f / (wsum * wsum);

    for (int i = tid; i < 32 * 32; i += NTHR) {
        int lx = i % 32, ly = i / 32;
        int gx = x0 - 8 + lx, gy = y0 - 8 + ly;
        float v = 0.f;
        if ((unsigned)gx < (unsigned)IMG && (unsigned)gy < (unsigned)IMG) {
            v = bilin(msm0, 10, 56, b0x, b0y, 0.25f,   gx, gy)
              + bilin(msm1, 6,  28, b1x, b1y, 0.125f,  gx, gy)
              + bilin(msm2, 3,  14, b2x, b2y, 0.0625f, gx, gy);
        }
        pre[i] = v;
    }
    __syncthreads();

    if (tid < 32 * 16) {
        int cx = tid % 16, ly = tid / 16;
        float acc = 0.f;
#pragma unroll
        for (int t = 0; t < 17; ++t) acc += wk[t] * pre[ly * 32 + cx + t];
        mid[ly * 16 + cx] = acc;
    }
    __syncthreads();

    if (tid < 16 * 16) {
        int ox = tid % 16, oy = tid / 16;
        float acc = 0.f;
#pragma unroll
        for (int t = 0; t < 17; ++t) acc += wk[t] * mid[(oy + t) * 16 + ox];
        out[1 + (y0 + oy) * IMG + (x0 + ox)] = acc * inv2;
    }
}

extern "C" void kernel_launch(void* const* d_in, const int* in_sizes, int n_in,
                              void* d_out, int out_size, void* d_ws, size_t ws_size,
                              hipStream_t stream) {
    const float* z    = (const float*)d_in[0];
    const float* f0   = (const float*)d_in[1];
    const float* f1   = (const float*)d_in[2];
    const float* f2   = (const float*)d_in[3];
    const float* zlib = (const float*)d_in[4];
    const float* l0   = (const float*)d_in[5];
    const float* l1   = (const float*)d_in[6];
    const float* l2   = (const float*)d_in[7];
    const int*   kp   = (const int*)d_in[8];
    float* out = (float*)d_out;

    float*    ws    = (float*)d_ws;
    float*    dists = ws;                       // 1000
    unsigned* d1    = (unsigned*)(ws + 1000);   // 125
    int*      idxs  = (int*)(ws + 1152);        // 8
    unsigned* b1    = (unsigned*)(ws + 1184);   // 196
    unsigned* rel   = (unsigned*)(ws + 1408);   // 196
    float*    s0    = ws + 1664;                // 2*MAXK*3136
    float*    s1    = s0 + 2 * MAXK * 3136;     // 4*MAXK*784
    float*    s2    = s1 + 4 * MAXK * 784;      // 8*MAXK*196

    k_dist_topk<<<KA_BLK, NTHR, 0, stream>>>(z, zlib, kp, dists, d1, idxs, out);
    k_main<<<KB_BLK, NTHR, 0, stream>>>(f0, f1, f2, l0, l1, l2, idxs, kp, out,
                                        b1, rel, s0, s1, s2);
}